// Round 1
// baseline (692.267 us; speedup 1.0000x reference)
//
#include <hip/hip_runtime.h>
#include <hip/hip_bf16.h>

#define BDIM 2048
#define WDIM 128
#define FDIM 8
#define HDIM 256

typedef __bf16 b8 __attribute__((ext_vector_type(8)));
typedef float f32x4 __attribute__((ext_vector_type(4)));

// workspace layout (bytes); all 16B-aligned
#define OFF_WHH 0                         // 48 NT x 8 kt x 64 lanes x 16B = 393216
#define OFF_WIH (OFF_WHH + 48*8*64*16)    // 48 NT x 64 x 16B = 49152
#define OFF_WP  (OFF_WIH + 48*64*16)      // 16 NT x 16 kt x 64 x 16B = 262144
#define OFF_XB  (OFF_WP + 16*16*64*16)    // 2048*128*8 bf16 = 4194304
// total = 4,898,816 B

#define MFMA(a, b, c) __builtin_amdgcn_mfma_f32_16x16x32_bf16((a), (b), (c), 0, 0, 0)

__device__ __forceinline__ float sigmoidf_(float v) { return 1.0f / (1.0f + __expf(-v)); }

// ---------------- pack: cast weights/x to bf16 in MFMA B-fragment layout ----------------
// B-frag (16x16x32): lane l holds B[k = kt*32 + 8*(l>>4) + e][col = NT*16 + (l&15)], e=0..7
__global__ void pack_kernel(const float* __restrict__ x,
                            const float* __restrict__ Wih_f,
                            const float* __restrict__ Whh_f,
                            const float* __restrict__ Wp,
                            unsigned char* __restrict__ ws)
{
    int idx = blockIdx.x * 256 + threadIdx.x;
    __bf16* whhP = (__bf16*)(ws + OFF_WHH);
    __bf16* wihP = (__bf16*)(ws + OFF_WIH);
    __bf16* wpP  = (__bf16*)(ws + OFF_WP);
    __bf16* xB   = (__bf16*)(ws + OFF_XB);

    if (idx < 24576) {                     // Whh fragments: B[k][n] = Whh[n][k]
        int l = idx & 63, nk = idx >> 6;
        int NT = nk >> 3, kt = nk & 7;
        int n = NT * 16 + (l & 15);
        int kb = kt * 32 + (l >> 4) * 8;
        b8 v;
        #pragma unroll
        for (int e = 0; e < 8; ++e) v[e] = (__bf16)Whh_f[n * HDIM + kb + e];
        *(b8*)(whhP + idx * 8) = v;
    } else if (idx < 24576 + 3072) {       // Wih fragments, K=8 zero-padded to 32
        int j = idx - 24576;
        int l = j & 63, NT = j >> 6;
        int n = NT * 16 + (l & 15);
        b8 v;
        #pragma unroll
        for (int e = 0; e < 8; ++e)
            v[e] = (l < 16) ? (__bf16)Wih_f[n * FDIM + e] : (__bf16)0.0f;
        *(b8*)(wihP + j * 8) = v;
    } else if (idx < 24576 + 3072 + 16384) {  // Wp fragments: B[k][col] = Wp[col][k]
        int j = idx - 27648;
        int l = j & 63, nk = j >> 6;
        int NT = nk >> 4, kt = nk & 15;
        int col = NT * 16 + (l & 15);
        int kb = kt * 32 + (l >> 4) * 8;
        b8 v;
        #pragma unroll
        for (int e = 0; e < 8; ++e) v[e] = (__bf16)Wp[col * (2 * HDIM) + kb + e];
        *(b8*)(wpP + j * 8) = v;
    } else if (idx < 44032 + 262144) {     // x -> bf16, 8 elems per item
        int j = idx - 44032;
        const float* src = x + j * 8;
        b8 v;
        #pragma unroll
        for (int e = 0; e < 8; ++e) v[e] = (__bf16)src[e];
        *(b8*)(xB + j * 8) = v;
    }
}

// ---------------- fused GRU + bwd cell + projection + LayerNorm ----------------
// 128 blocks x 512 threads (8 waves). Block owns 16 batch rows.
// Wave w owns columns [32w, 32w+32) of EACH gate (2 n-tiles per gate).
__global__ __launch_bounds__(512, 1)
void gru_main_kernel(const float* __restrict__ x,
                     const float* __restrict__ bih_f, const float* __restrict__ bhh_f,
                     const float* __restrict__ Wih_b, const float* __restrict__ bih_b,
                     const float* __restrict__ bhh_b,
                     const float* __restrict__ bp,
                     const float* __restrict__ gamma, const float* __restrict__ beta,
                     const unsigned char* __restrict__ ws,
                     float* __restrict__ out)
{
    // LDS overlay: [0,32K) hf[2][16][256] f32 ; [32K,48K) hbuf[2][16][256] bf16
    // tail reuses: [32K,48K) lastb[16][512] bf16 ; [48K,64K) ybuf[16][256] f32
    __shared__ __align__(16) unsigned char smem[65536];
    float  (*hf)[16][HDIM]    = reinterpret_cast<float(*)[16][HDIM]>(smem);
    __bf16 (*hbuf)[16][HDIM]  = reinterpret_cast<__bf16(*)[16][HDIM]>(smem + 32768);
    __bf16 (*lastb)[2 * HDIM] = reinterpret_cast<__bf16(*)[2 * HDIM]>(smem + 32768);
    float  (*ybuf)[HDIM]      = reinterpret_cast<float(*)[HDIM]>(smem + 49152);

    const int tid = threadIdx.x;
    const int lane = tid & 63;
    const int w = tid >> 6;                  // wave 0..7
    const int blockRow = blockIdx.x * 16;

    const b8* whhP = (const b8*)(ws + OFF_WHH);
    const b8* wihP = (const b8*)(ws + OFF_WIH);
    const b8* wpP  = (const b8*)(ws + OFF_WP);
    const b8* xB   = (const b8*)(ws + OFF_XB);

    // h0 = 0
    for (int i = tid; i < 16 * HDIM; i += 512) {
        hf[0][i >> 8][i & 255] = 0.0f;
        hbuf[0][i >> 8][i & 255] = (__bf16)0.0f;
    }

    const int l15 = lane & 15;
    const int lq = lane >> 4;                // 0..3
    // per-lane biases: acc_r/z init = bih+bhh ; n-gate split: x-part(bih) vs h-part(bhh)
    float bR[2], bZ[2], bNH[2], bNX[2];
    b8 wih[3][2];
    #pragma unroll
    for (int nt = 0; nt < 2; ++nt) {
        int ch = 32 * w + nt * 16 + l15;
        bR[nt]  = bih_f[ch] + bhh_f[ch];
        bZ[nt]  = bih_f[HDIM + ch] + bhh_f[HDIM + ch];
        bNX[nt] = bih_f[2 * HDIM + ch];
        bNH[nt] = bhh_f[2 * HDIM + ch];
        #pragma unroll
        for (int g = 0; g < 3; ++g)
            wih[g][nt] = wihP[(g * 16 + 2 * w + nt) * 64 + lane];
    }
    __syncthreads();

    const int arow = l15;                    // A-frag: row = lane&15, k = kt*32 + 8*(lane>>4)+e
    const int akoff = lq * 8;

    for (int t = 0; t < WDIM; ++t) {
        const int cur = t & 1, nxt = cur ^ 1;

        // x A-fragment (K=8 real, rest zero)
        b8 ax;
        #pragma unroll
        for (int e = 0; e < 8; ++e) ax[e] = (__bf16)0.0f;
        if (lane < 16) ax = xB[(blockRow + l15) * WDIM + t];

        f32x4 aR[2], aZ[2], aNH[2], aNX[2];
        #pragma unroll
        for (int nt = 0; nt < 2; ++nt) {
            aR[nt]  = (f32x4){bR[nt], bR[nt], bR[nt], bR[nt]};
            aZ[nt]  = (f32x4){bZ[nt], bZ[nt], bZ[nt], bZ[nt]};
            aNH[nt] = (f32x4){bNH[nt], bNH[nt], bNH[nt], bNH[nt]};
            aNX[nt] = (f32x4){bNX[nt], bNX[nt], bNX[nt], bNX[nt]};
            aR[nt]  = MFMA(ax, wih[0][nt], aR[nt]);
            aZ[nt]  = MFMA(ax, wih[1][nt], aZ[nt]);
            aNX[nt] = MFMA(ax, wih[2][nt], aNX[nt]);
        }

        // h @ Whh^T : stream B-frags from L2, A-frags from swizzled LDS
        #pragma unroll
        for (int kt = 0; kt < 8; ++kt) {
            int c = (kt * 32 + akoff) ^ ((arow & 7) << 3);   // XOR-swizzle (G4)
            b8 a = *(const b8*)&hbuf[cur][arow][c];
            #pragma unroll
            for (int nt = 0; nt < 2; ++nt) {
                int nts = 2 * w + nt;
                aR[nt]  = MFMA(a, whhP[((0  + nts) * 8 + kt) * 64 + lane], aR[nt]);
                aZ[nt]  = MFMA(a, whhP[((16 + nts) * 8 + kt) * 64 + lane], aZ[nt]);
                aNH[nt] = MFMA(a, whhP[((32 + nts) * 8 + kt) * 64 + lane], aNH[nt]);
            }
        }

        // gate fusion; C layout: col = lane&15, row = 4*(lane>>4)+j
        #pragma unroll
        for (int nt = 0; nt < 2; ++nt) {
            int ch = 32 * w + nt * 16 + l15;
            #pragma unroll
            for (int j = 0; j < 4; ++j) {
                int row = lq * 4 + j;
                float r = sigmoidf_(aR[nt][j]);
                float z = sigmoidf_(aZ[nt][j]);
                float n = tanhf(fmaf(r, aNH[nt][j], aNX[nt][j]));
                float hold = hf[cur][row][ch];
                float hnew = n + z * (hold - n);   // (1-z)*n + z*h
                hf[nxt][row][ch] = hnew;
                hbuf[nxt][row][ch ^ ((row & 7) << 3)] = (__bf16)hnew;
            }
        }
        __syncthreads();
    }
    // final h is in buffer 0 (t=127: nxt=0)

    // ---- backward cell (h0=0 -> one step on x[:,127,:]) + build `last` ----
    {
        const int trow = tid >> 5;           // 0..15
        const int cb = tid & 31;
        const float4* xr = (const float4*)(x + (blockRow + trow) * WDIM * FDIM + 127 * FDIM);
        float4 xv0 = xr[0], xv1 = xr[1];
        const float4* wb = (const float4*)Wih_b;
        #pragma unroll
        for (int jj = 0; jj < 8; ++jj) {
            int ch = cb + 32 * jj;
            lastb[trow][ch ^ ((trow & 7) << 3)] = (__bf16)hf[0][trow][ch];

            float4 a0 = wb[ch * 2],              a1 = wb[ch * 2 + 1];
            float4 b0 = wb[(HDIM + ch) * 2],     b1 = wb[(HDIM + ch) * 2 + 1];
            float4 c0 = wb[(2 * HDIM + ch) * 2], c1 = wb[(2 * HDIM + ch) * 2 + 1];
            float ir = bih_b[ch]
                + xv0.x * a0.x + xv0.y * a0.y + xv0.z * a0.z + xv0.w * a0.w
                + xv1.x * a1.x + xv1.y * a1.y + xv1.z * a1.z + xv1.w * a1.w;
            float iz = bih_b[HDIM + ch]
                + xv0.x * b0.x + xv0.y * b0.y + xv0.z * b0.z + xv0.w * b0.w
                + xv1.x * b1.x + xv1.y * b1.y + xv1.z * b1.z + xv1.w * b1.w;
            float inn = bih_b[2 * HDIM + ch]
                + xv0.x * c0.x + xv0.y * c0.y + xv0.z * c0.z + xv0.w * c0.w
                + xv1.x * c1.x + xv1.y * c1.y + xv1.z * c1.z + xv1.w * c1.w;
            float r = sigmoidf_(ir + bhh_b[ch]);
            float z = sigmoidf_(iz + bhh_b[HDIM + ch]);
            float n = tanhf(fmaf(r, bhh_b[2 * HDIM + ch], inn));
            float hbw = (1.0f - z) * n;
            int c2 = HDIM + ch;
            lastb[trow][c2 ^ ((trow & 7) << 3)] = (__bf16)hbw;
        }
    }
    __syncthreads();

    // ---- projection: y = gelu(last @ Wp^T + bp), wave w -> cols [32w,32w+32) ----
    {
        f32x4 pacc[2];
        #pragma unroll
        for (int nt = 0; nt < 2; ++nt) {
            int col = 32 * w + nt * 16 + l15;
            float b = bp[col];
            pacc[nt] = (f32x4){b, b, b, b};
        }
        #pragma unroll
        for (int kt = 0; kt < 16; ++kt) {
            int c = (kt * 32 + akoff) ^ ((arow & 7) << 3);
            b8 a = *(const b8*)&lastb[arow][c];
            #pragma unroll
            for (int nt = 0; nt < 2; ++nt)
                pacc[nt] = MFMA(a, wpP[((2 * w + nt) * 16 + kt) * 64 + lane], pacc[nt]);
        }
        #pragma unroll
        for (int nt = 0; nt < 2; ++nt) {
            int col = 32 * w + nt * 16 + l15;
            #pragma unroll
            for (int j = 0; j < 4; ++j) {
                int row = lq * 4 + j;
                float v = pacc[nt][j];
                ybuf[row][col] = 0.5f * v * (1.0f + erff(v * 0.70710678118f)); // exact gelu
            }
        }
    }
    __syncthreads();

    // ---- LayerNorm: one wave per 2 rows, 4 cols/lane, shuffle reduce ----
    #pragma unroll
    for (int rr = 0; rr < 2; ++rr) {
        int row = 2 * w + rr;
        float v[4];
        float s = 0.0f, sq = 0.0f;
        #pragma unroll
        for (int m = 0; m < 4; ++m) {
            v[m] = ybuf[row][lane + 64 * m];
            s += v[m];
            sq += v[m] * v[m];
        }
        #pragma unroll
        for (int off = 32; off >= 1; off >>= 1) {
            s  += __shfl_xor(s, off, 64);
            sq += __shfl_xor(sq, off, 64);
        }
        float mu = s * (1.0f / 256.0f);
        float var = sq * (1.0f / 256.0f) - mu * mu;   // biased, matches jnp.var
        float rs = rsqrtf(var + 1e-5f);
        float* orow = out + (blockRow + row) * HDIM;
        #pragma unroll
        for (int m = 0; m < 4; ++m) {
            int cc = lane + 64 * m;
            orow[cc] = (v[m] - mu) * rs * gamma[cc] + beta[cc];
        }
    }
}

extern "C" void kernel_launch(void* const* d_in, const int* in_sizes, int n_in,
                              void* d_out, int out_size, void* d_ws, size_t ws_size,
                              hipStream_t stream)
{
    const float* x     = (const float*)d_in[0];
    const float* Wih_f = (const float*)d_in[1];
    const float* Whh_f = (const float*)d_in[2];
    const float* bih_f = (const float*)d_in[3];
    const float* bhh_f = (const float*)d_in[4];
    const float* Wih_b = (const float*)d_in[5];
    // d_in[6] = Whh_b unused: h0=0 so gh_b = bhh_b exactly
    const float* bih_b = (const float*)d_in[7];
    const float* bhh_b = (const float*)d_in[8];
    const float* Wp    = (const float*)d_in[9];
    const float* bp    = (const float*)d_in[10];
    const float* gamma = (const float*)d_in[11];
    const float* beta  = (const float*)d_in[12];
    float* out = (float*)d_out;
    unsigned char* ws = (unsigned char*)d_ws;

    const int packItems = 24576 + 3072 + 16384 + 262144;   // = 306176
    hipLaunchKernelGGL(pack_kernel, dim3((packItems + 255) / 256), dim3(256), 0, stream,
                       x, Wih_f, Whh_f, Wp, ws);
    hipLaunchKernelGGL(gru_main_kernel, dim3(BDIM / 16), dim3(512), 0, stream,
                       x, bih_f, bhh_f, Wih_b, bih_b, bhh_b, bp, gamma, beta, ws, out);
}

// Round 3
// 397.163 us; speedup vs baseline: 1.7430x; 1.7430x over previous
//
#include <hip/hip_runtime.h>
#include <hip/hip_bf16.h>

#define BDIM 2048
#define WDIM 128
#define FDIM 8
#define HDIM 256

typedef __bf16 b8 __attribute__((ext_vector_type(8)));
typedef __bf16 b4 __attribute__((ext_vector_type(4)));
typedef float f32x4 __attribute__((ext_vector_type(4)));

// workspace layout (bytes), all 16B aligned
#define OFF_RZ  0                 // 256 frags * 1KB = 262144 (r,z Whh A-frags)
#define OFF_N   262144            // 128 frags * 1KB = 131072 (n Whh A-frags, streamed)
#define OFF_WIH 393216            // 48 frags * 1KB = 49152  (Wih A-frags + bias in k=8)
#define OFF_WP  442368            // 256 frags * 1KB = 262144 (Wp B-frags)
#define OFF_XB  704512            // 2048*128*8 bf16 = 4194304
// total 4,898,816 B

#define MFMA(a,b,c) __builtin_amdgcn_mfma_f32_16x16x32_bf16((a),(b),(c),0,0,0)

static __device__ __forceinline__ float sig_(float v) {
    return __builtin_amdgcn_rcpf(1.0f + __expf(-v));
}
static __device__ __forceinline__ float tanh_(float v) {
    // tanh(v) = 1 - 2/(exp(2v)+1); saturates correctly at +-inf
    return fmaf(-2.0f, __builtin_amdgcn_rcpf(1.0f + __expf(2.0f * v)), 1.0f);
}

// ---------------- pack: weights/x -> bf16 MFMA fragments ----------------
// A-frag (16x16x32): lane l holds A[i = l&15][k = kt*32 + (l>>4)*8 + e]
// B-frag:            lane l holds B[k = kt*32 + (l>>4)*8 + e][j = l&15]
__global__ void pack_kernel(const float* __restrict__ x,
                            const float* __restrict__ Wih_f,
                            const float* __restrict__ Whh_f,
                            const float* __restrict__ bih_f,
                            const float* __restrict__ bhh_f,
                            const float* __restrict__ Wp,
                            unsigned char* __restrict__ ws)
{
    int idx = blockIdx.x * 256 + threadIdx.x;
    if (idx < 16384) {                       // r,z Whh A-frags: f = (w*4+2g+nt)*8+kt
        int l = idx & 63, f = idx >> 6;
        int kt = f & 7, nt = (f >> 3) & 1, g = (f >> 4) & 1, w = f >> 5;
        int gch = g * HDIM + 32 * w + 16 * nt + (l & 15);
        int kb = kt * 32 + (l >> 4) * 8;
        b8 v;
        #pragma unroll
        for (int e = 0; e < 8; ++e) v[e] = (__bf16)Whh_f[gch * HDIM + kb + e];
        ((b8*)(ws + OFF_RZ))[idx] = v;
    } else if (idx < 24576) {                // n Whh A-frags: f = (w*2+nt)*8+kt
        int j = idx - 16384;
        int l = j & 63, f = j >> 6;
        int kt = f & 7, nt = (f >> 3) & 1, w = f >> 4;
        int gch = 2 * HDIM + 32 * w + 16 * nt + (l & 15);
        int kb = kt * 32 + (l >> 4) * 8;
        b8 v;
        #pragma unroll
        for (int e = 0; e < 8; ++e) v[e] = (__bf16)Whh_f[gch * HDIM + kb + e];
        ((b8*)(ws + OFF_N))[j] = v;
    } else if (idx < 27648) {                // Wih A-frags (K=8 real, bias at k=8)
        int j = idx - 24576;
        int l = j & 63, f = j >> 6;
        int nt = f & 1, q = f >> 1, g = q % 3, w = q / 3;
        int gch = g * HDIM + 32 * w + 16 * nt + (l & 15);
        int lq = l >> 4;
        b8 v;
        #pragma unroll
        for (int e = 0; e < 8; ++e) v[e] = (__bf16)0.0f;
        if (lq == 0) {
            #pragma unroll
            for (int e = 0; e < 8; ++e) v[e] = (__bf16)Wih_f[gch * FDIM + e];
        } else if (lq == 1) {
            float b = (g == 2) ? bih_f[gch] : (bih_f[gch] + bhh_f[gch]);
            v[0] = (__bf16)b;                // pairs with 1.0 in x B-frag k=8
        }
        ((b8*)(ws + OFF_WIH))[j] = v;
    } else if (idx < 44032) {                // Wp B-frags
        int j = idx - 27648;
        int l = j & 63, nk = j >> 6;
        int NT = nk >> 4, kt = nk & 15;
        int col = NT * 16 + (l & 15);
        int kb = kt * 32 + (l >> 4) * 8;
        b8 v;
        #pragma unroll
        for (int e = 0; e < 8; ++e) v[e] = (__bf16)Wp[col * (2 * HDIM) + kb + e];
        ((b8*)(ws + OFF_WP))[j] = v;
    } else if (idx < 44032 + 262144) {       // x -> bf16 rows [row][t][8]
        int j = idx - 44032;
        const float* src = x + j * 8;
        b8 v;
        #pragma unroll
        for (int e = 0; e < 8; ++e) v[e] = (__bf16)src[e];
        ((b8*)(ws + OFF_XB))[j] = v;
    }
}

// ---------------- fused GRU (transposed MFMA, weights in regs) ----------------
// 128 blocks x 512 threads (8 waves). Block owns 16 batch rows.
// Wave w owns gate channels [32w, 32w+32) of r, z, n (as M-tiles).
// D[i=gatech][j=batchrow]: lane holds batchrow = l&15, gatech = 4*(l>>4)+j.
__global__ __launch_bounds__(512, 2)
void gru_main_kernel(const float* __restrict__ x,
                     const float* __restrict__ bhh_f,
                     const float* __restrict__ Wih_b, const float* __restrict__ bih_b,
                     const float* __restrict__ bhh_b,
                     const float* __restrict__ bp,
                     const float* __restrict__ gamma, const float* __restrict__ beta,
                     const unsigned char* __restrict__ ws,
                     float* __restrict__ out)
{
    // smem: loop: [0,16K) hbuf[2][16][256] bf16 (XOR-swizzled)
    //       tail: [0,16K) lastb[16][512] bf16 ; [16K,32K) ybuf[16][256] f32
    __shared__ __align__(16) unsigned char smem[32768];
    __bf16* hbB = (__bf16*)smem;
    __bf16 (*lastb)[2 * HDIM] = (__bf16(*)[2 * HDIM])smem;
    float  (*ybuf)[HDIM]      = (float(*)[HDIM])(smem + 16384);

    const int tid = threadIdx.x, lane = tid & 63, w = tid >> 6;
    const int l15 = lane & 15, lq = lane >> 4;
    const int blockRow = blockIdx.x * 16;

    const b8* wsRZ = (const b8*)(ws + OFF_RZ);
    const b8* wsN  = (const b8*)(ws + OFF_N);
    const b8* wsWI = (const b8*)(ws + OFF_WIH);
    const b8* wsWP = (const b8*)(ws + OFF_WP);
    const b8* xB   = (const b8*)(ws + OFF_XB);

    const f32x4 zero4 = {0.f, 0.f, 0.f, 0.f};

    // zero hbuf (both buffers): 512 threads x 16B x 2
    *(f32x4*)(smem + tid * 16) = zero4;
    *(f32x4*)(smem + 8192 + tid * 16) = zero4;

    // register-resident A-frags: r,z Whh (32 frags) + Wih (6 frags)
    b8 whr[2][8], whz[2][8], wir[2], wiz[2], win[2];
    #pragma unroll
    for (int nt = 0; nt < 2; ++nt) {
        #pragma unroll
        for (int kt = 0; kt < 8; ++kt) {
            whr[nt][kt] = wsRZ[((w * 4 + 0 + nt) * 8 + kt) * 64 + lane];
            whz[nt][kt] = wsRZ[((w * 4 + 2 + nt) * 8 + kt) * 64 + lane];
        }
        wir[nt] = wsWI[((w * 3 + 0) * 2 + nt) * 64 + lane];
        wiz[nt] = wsWI[((w * 3 + 1) * 2 + nt) * 64 + lane];
        win[nt] = wsWI[((w * 3 + 2) * 2 + nt) * 64 + lane];
    }

    // bhh_n accumulator-init values (C reg j <-> gatech 4*lq+j)
    const float4 bnv0 = *(const float4*)&bhh_f[2 * HDIM + 32 * w + 0  + 4 * lq];
    const float4 bnv1 = *(const float4*)&bhh_f[2 * HDIM + 32 * w + 16 + 4 * lq];

    // constant part of x B-frag: k=8 -> 1.0 (bias multiplier), rest 0
    b8 xc;
    #pragma unroll
    for (int e = 0; e < 8; ++e) xc[e] = (__bf16)0.0f;
    if (lq == 1) xc[0] = (__bf16)1.0f;

    // h master state in registers: (row=l15, ch=32w+16nt+4lq+j)
    f32x4 h0 = zero4, h1 = zero4;

    const int kswz = (8 * lq) ^ ((l15 & 7) << 3);     // B-read swizzle base
    const int wswz = (l15 & 7) << 3;                  // write swizzle
    const b8* nhW = wsN + (w * 16) * 64 + lane;       // streamed n-gate frags

    __syncthreads();

    int cur = 0;
    for (int t = 0; t < WDIM; ++t) {
        b8 xf = xc;
        if (lane < 16) xf = xB[(blockRow + l15) * WDIM + t];

        const __bf16* hc = hbB + cur * 4096 + l15 * 256;

        f32x4 aR0 = zero4, aR1 = zero4;
        f32x4 aZ0 = zero4, aZ1 = zero4;
        f32x4 aNH0, aNH1;
        aNH0[0] = bnv0.x; aNH0[1] = bnv0.y; aNH0[2] = bnv0.z; aNH0[3] = bnv0.w;
        aNH1[0] = bnv1.x; aNH1[1] = bnv1.y; aNH1[2] = bnv1.z; aNH1[3] = bnv1.w;

        #pragma unroll
        for (int kt = 0; kt < 8; ++kt) {
            b8 hfrag = *(const b8*)(hc + ((kt << 5) ^ kswz));
            b8 n0 = nhW[kt * 64];          // loop-invariant addresses, L2-served
            b8 n1 = nhW[(8 + kt) * 64];
            aR0  = MFMA(whr[0][kt], hfrag, aR0);
            aR1  = MFMA(whr[1][kt], hfrag, aR1);
            aZ0  = MFMA(whz[0][kt], hfrag, aZ0);
            aZ1  = MFMA(whz[1][kt], hfrag, aZ1);
            aNH0 = MFMA(n0, hfrag, aNH0);
            aNH1 = MFMA(n1, hfrag, aNH1);
        }
        // x-part (+ biases via k=8 slot)
        aR0 = MFMA(wir[0], xf, aR0);
        aR1 = MFMA(wir[1], xf, aR1);
        aZ0 = MFMA(wiz[0], xf, aZ0);
        aZ1 = MFMA(wiz[1], xf, aZ1);
        f32x4 aNX0 = MFMA(win[0], xf, zero4);
        f32x4 aNX1 = MFMA(win[1], xf, zero4);

        // gate fusion (h master in regs)
        __bf16* hn = hbB + (cur ^ 1) * 4096;
        b4 v0, v1;
        #pragma unroll
        for (int j = 0; j < 4; ++j) {
            float r = sig_(aR0[j]);
            float z = sig_(aZ0[j]);
            float n = tanh_(fmaf(r, aNH0[j], aNX0[j]));
            float hv = n + z * (h0[j] - n);
            h0[j] = hv; v0[j] = (__bf16)hv;
            r = sig_(aR1[j]);
            z = sig_(aZ1[j]);
            n = tanh_(fmaf(r, aNH1[j], aNX1[j]));
            hv = n + z * (h1[j] - n);
            h1[j] = hv; v1[j] = (__bf16)hv;
        }
        *(b4*)(hn + l15 * 256 + ((32 * w + 0  + 4 * lq) ^ wswz)) = v0;
        *(b4*)(hn + l15 * 256 + ((32 * w + 16 + 4 * lq) ^ wswz)) = v1;

        cur ^= 1;
        __syncthreads();
    }

    // ---- write forward h (f32 regs) into lastb cols [0,256) ----
    {
        b4 v0, v1;
        #pragma unroll
        for (int j = 0; j < 4; ++j) { v0[j] = (__bf16)h0[j]; v1[j] = (__bf16)h1[j]; }
        *(b4*)(&lastb[l15][0] + ((32 * w + 0  + 4 * lq) ^ wswz)) = v0;
        *(b4*)(&lastb[l15][0] + ((32 * w + 16 + 4 * lq) ^ wswz)) = v1;
    }

    // ---- backward cell (h0=0, one step on x[:,127,:]) -> lastb cols [256,512) ----
    {
        const int trow = tid >> 5;           // 0..15
        const int cb = tid & 31;
        const float4* xr = (const float4*)(x + (blockRow + trow) * WDIM * FDIM + 127 * FDIM);
        float4 xv0 = xr[0], xv1 = xr[1];
        const float4* wb = (const float4*)Wih_b;
        #pragma unroll
        for (int jj = 0; jj < 8; ++jj) {
            int ch = cb + 32 * jj;
            float4 a0 = wb[ch * 2],              a1 = wb[ch * 2 + 1];
            float4 b0 = wb[(HDIM + ch) * 2],     b1 = wb[(HDIM + ch) * 2 + 1];
            float4 c0 = wb[(2 * HDIM + ch) * 2], c1 = wb[(2 * HDIM + ch) * 2 + 1];
            float ir = bih_b[ch]
                + xv0.x * a0.x + xv0.y * a0.y + xv0.z * a0.z + xv0.w * a0.w
                + xv1.x * a1.x + xv1.y * a1.y + xv1.z * a1.z + xv1.w * a1.w;
            float iz = bih_b[HDIM + ch]
                + xv0.x * b0.x + xv0.y * b0.y + xv0.z * b0.z + xv0.w * b0.w
                + xv1.x * b1.x + xv1.y * b1.y + xv1.z * b1.z + xv1.w * b1.w;
            float inn = bih_b[2 * HDIM + ch]
                + xv0.x * c0.x + xv0.y * c0.y + xv0.z * c0.z + xv0.w * c0.w
                + xv1.x * c1.x + xv1.y * c1.y + xv1.z * c1.z + xv1.w * c1.w;
            float r = sig_(ir + bhh_b[ch]);
            float z = sig_(iz + bhh_b[HDIM + ch]);
            float n = tanh_(fmaf(r, bhh_b[2 * HDIM + ch], inn));
            float hbw = (1.0f - z) * n;
            int c2 = HDIM + ch;
            lastb[trow][c2 ^ ((trow & 7) << 3)] = (__bf16)hbw;
        }
    }
    __syncthreads();

    // ---- projection: y = gelu(last @ Wp^T + bp); wave w -> cols [32w,32w+32) ----
    {
        f32x4 pacc[2];
        #pragma unroll
        for (int nt = 0; nt < 2; ++nt) {
            int col = 32 * w + nt * 16 + l15;
            float b = bp[col];
            pacc[nt][0] = b; pacc[nt][1] = b; pacc[nt][2] = b; pacc[nt][3] = b;
        }
        #pragma unroll
        for (int kt = 0; kt < 16; ++kt) {
            int c = (kt * 32 + lq * 8) ^ ((l15 & 7) << 3);
            b8 a = *(const b8*)&lastb[l15][c];
            #pragma unroll
            for (int nt = 0; nt < 2; ++nt)
                pacc[nt] = MFMA(a, wsWP[((2 * w + nt) * 16 + kt) * 64 + lane], pacc[nt]);
        }
        #pragma unroll
        for (int nt = 0; nt < 2; ++nt) {
            int col = 32 * w + nt * 16 + l15;
            #pragma unroll
            for (int j = 0; j < 4; ++j) {
                int row = lq * 4 + j;
                float v = pacc[nt][j];
                ybuf[row][col] = 0.5f * v * (1.0f + erff(v * 0.70710678118f));
            }
        }
    }
    __syncthreads();

    // ---- LayerNorm: one wave per 2 rows ----
    #pragma unroll
    for (int rr = 0; rr < 2; ++rr) {
        int row = 2 * w + rr;
        float v[4];
        float s = 0.0f, sq = 0.0f;
        #pragma unroll
        for (int m = 0; m < 4; ++m) {
            v[m] = ybuf[row][lane + 64 * m];
            s += v[m];
            sq += v[m] * v[m];
        }
        #pragma unroll
        for (int off = 32; off >= 1; off >>= 1) {
            s  += __shfl_xor(s, off, 64);
            sq += __shfl_xor(sq, off, 64);
        }
        float mu = s * (1.0f / 256.0f);
        float var = sq * (1.0f / 256.0f) - mu * mu;
        float rs = rsqrtf(var + 1e-5f);
        float* orow = out + (blockRow + row) * HDIM;
        #pragma unroll
        for (int m = 0; m < 4; ++m) {
            int cc = lane + 64 * m;
            orow[cc] = (v[m] - mu) * rs * gamma[cc] + beta[cc];
        }
    }
}

extern "C" void kernel_launch(void* const* d_in, const int* in_sizes, int n_in,
                              void* d_out, int out_size, void* d_ws, size_t ws_size,
                              hipStream_t stream)
{
    const float* x     = (const float*)d_in[0];
    const float* Wih_f = (const float*)d_in[1];
    const float* Whh_f = (const float*)d_in[2];
    const float* bih_f = (const float*)d_in[3];
    const float* bhh_f = (const float*)d_in[4];
    const float* Wih_b = (const float*)d_in[5];
    // d_in[6] = Whh_b unused: h0=0 so gh_b = bhh_b exactly
    const float* bih_b = (const float*)d_in[7];
    const float* bhh_b = (const float*)d_in[8];
    const float* Wp    = (const float*)d_in[9];
    const float* bp    = (const float*)d_in[10];
    const float* gamma = (const float*)d_in[11];
    const float* beta  = (const float*)d_in[12];
    float* out = (float*)d_out;
    unsigned char* ws = (unsigned char*)d_ws;

    const int packItems = 16384 + 8192 + 3072 + 16384 + 262144;   // 306176
    hipLaunchKernelGGL(pack_kernel, dim3((packItems + 255) / 256), dim3(256), 0, stream,
                       x, Wih_f, Whh_f, bih_f, bhh_f, Wp, ws);
    hipLaunchKernelGGL(gru_main_kernel, dim3(BDIM / 16), dim3(512), 0, stream,
                       x, bhh_f, Wih_b, bih_b, bhh_b, bp, gamma, beta, ws, out);
}

// Round 4
// 216.015 us; speedup vs baseline: 3.2047x; 1.8386x over previous
//
#include <hip/hip_runtime.h>
#include <hip/hip_bf16.h>

#define BDIM 2048
#define WDIM 128
#define FDIM 8
#define HDIM 256

typedef __bf16 b8 __attribute__((ext_vector_type(8)));
typedef __bf16 b4 __attribute__((ext_vector_type(4)));
typedef float f32x4 __attribute__((ext_vector_type(4)));

// workspace layout (bytes), all 16B aligned
#define OFF_RZ  0                 // 256 frags * 1KB = 262144 (r,z Whh A-frags)
#define OFF_N   262144            // 128 frags * 1KB = 131072 (n Whh A-frags -> LDS)
#define OFF_WIH 393216            // 48 frags * 1KB = 49152  (Wih A-frags + bias in k=8)
#define OFF_WP  442368            // 256 frags * 1KB = 262144 (Wp B-frags)
#define OFF_XB  704512            // 2048*128*8 bf16 = 4194304
// total 4,898,816 B

// dynamic LDS layout (bytes): [0,16K) h dbuf (2x8KB) ; [16K,144K) n-gate frags
// tail overlay: [0,16K) lastb[16][512] bf16 ; [16K,32K) ybuf[16][256] f32
#define SMEM_BYTES 147456

#define MFMA(a,b,c) __builtin_amdgcn_mfma_f32_16x16x32_bf16((a),(b),(c),0,0,0)

static __device__ __forceinline__ float sig_(float v) {
    return __builtin_amdgcn_rcpf(1.0f + __expf(-v));
}
static __device__ __forceinline__ float tanh_(float v) {
    // tanh(v) = 1 - 2/(exp(2v)+1); saturates correctly at +-inf
    return fmaf(-2.0f, __builtin_amdgcn_rcpf(1.0f + __expf(2.0f * v)), 1.0f);
}

// ---------------- pack: weights/x -> bf16 MFMA fragments ----------------
// A-frag (16x16x32): lane l holds A[i = l&15][k = kt*32 + (l>>4)*8 + e]
// B-frag:            lane l holds B[k = kt*32 + (l>>4)*8 + e][j = l&15]
__global__ void pack_kernel(const float* __restrict__ x,
                            const float* __restrict__ Wih_f,
                            const float* __restrict__ Whh_f,
                            const float* __restrict__ bih_f,
                            const float* __restrict__ bhh_f,
                            const float* __restrict__ Wp,
                            unsigned char* __restrict__ ws)
{
    int idx = blockIdx.x * 256 + threadIdx.x;
    if (idx < 16384) {                       // r,z Whh A-frags: f = (w*4+2g+nt)*8+kt
        int l = idx & 63, f = idx >> 6;
        int kt = f & 7, nt = (f >> 3) & 1, g = (f >> 4) & 1, w = f >> 5;
        int gch = g * HDIM + 32 * w + 16 * nt + (l & 15);
        int kb = kt * 32 + (l >> 4) * 8;
        b8 v;
        #pragma unroll
        for (int e = 0; e < 8; ++e) v[e] = (__bf16)Whh_f[gch * HDIM + kb + e];
        ((b8*)(ws + OFF_RZ))[idx] = v;
    } else if (idx < 24576) {                // n Whh A-frags: f = (w*2+nt)*8+kt
        int j = idx - 16384;
        int l = j & 63, f = j >> 6;
        int kt = f & 7, nt = (f >> 3) & 1, w = f >> 4;
        int gch = 2 * HDIM + 32 * w + 16 * nt + (l & 15);
        int kb = kt * 32 + (l >> 4) * 8;
        b8 v;
        #pragma unroll
        for (int e = 0; e < 8; ++e) v[e] = (__bf16)Whh_f[gch * HDIM + kb + e];
        ((b8*)(ws + OFF_N))[j] = v;
    } else if (idx < 27648) {                // Wih A-frags (K=8 real, bias at k=8)
        int j = idx - 24576;
        int l = j & 63, f = j >> 6;
        int nt = f & 1, q = f >> 1, g = q % 3, w = q / 3;
        int gch = g * HDIM + 32 * w + 16 * nt + (l & 15);
        int lq = l >> 4;
        b8 v;
        #pragma unroll
        for (int e = 0; e < 8; ++e) v[e] = (__bf16)0.0f;
        if (lq == 0) {
            #pragma unroll
            for (int e = 0; e < 8; ++e) v[e] = (__bf16)Wih_f[gch * FDIM + e];
        } else if (lq == 1) {
            float b = (g == 2) ? bih_f[gch] : (bih_f[gch] + bhh_f[gch]);
            v[0] = (__bf16)b;                // pairs with 1.0 in x B-frag k=8
        }
        ((b8*)(ws + OFF_WIH))[j] = v;
    } else if (idx < 44032) {                // Wp B-frags
        int j = idx - 27648;
        int l = j & 63, nk = j >> 6;
        int NT = nk >> 4, kt = nk & 15;
        int col = NT * 16 + (l & 15);
        int kb = kt * 32 + (l >> 4) * 8;
        b8 v;
        #pragma unroll
        for (int e = 0; e < 8; ++e) v[e] = (__bf16)Wp[col * (2 * HDIM) + kb + e];
        ((b8*)(ws + OFF_WP))[j] = v;
    } else if (idx < 44032 + 262144) {       // x -> bf16 rows [row][t][8]
        int j = idx - 44032;
        const float* src = x + j * 8;
        b8 v;
        #pragma unroll
        for (int e = 0; e < 8; ++e) v[e] = (__bf16)src[e];
        ((b8*)(ws + OFF_XB))[j] = v;
    }
}

// ---------------- fused GRU (transposed MFMA) ----------------
// 128 blocks x 512 threads (8 waves). Block owns 16 batch rows.
// Wave w owns gate channels [32w, 32w+32) of r, z, n (as M-tiles).
// r,z weights pinned in VGPRs; n weights in LDS; h master state in VGPRs.
// D[i=gatech][j=batchrow]: lane holds batchrow = l&15, gatech = 4*(l>>4)+j.
__global__ __launch_bounds__(512, 2)
void gru_main_kernel(const float* __restrict__ x,
                     const float* __restrict__ bhh_f,
                     const float* __restrict__ Wih_b, const float* __restrict__ bih_b,
                     const float* __restrict__ bhh_b,
                     const float* __restrict__ bp,
                     const float* __restrict__ gamma, const float* __restrict__ beta,
                     const unsigned char* __restrict__ ws,
                     float* __restrict__ out)
{
    extern __shared__ __align__(16) unsigned char smem[];
    __bf16* hbB = (__bf16*)smem;                            // [0,16K) h dbuf
    b8* nlds = (b8*)(smem + 16384);                         // [16K,144K) n frags
    __bf16 (*lastb)[2 * HDIM] = (__bf16(*)[2 * HDIM])smem;  // tail overlay
    float  (*ybuf)[HDIM]      = (float(*)[HDIM])(smem + 16384);

    const int tid = threadIdx.x, lane = tid & 63, w = tid >> 6;
    const int l15 = lane & 15, lq = lane >> 4;
    const int blockRow = blockIdx.x * 16;

    const b8* wsRZ = (const b8*)(ws + OFF_RZ);
    const b8* wsN  = (const b8*)(ws + OFF_N);
    const b8* wsWI = (const b8*)(ws + OFF_WIH);
    const b8* wsWP = (const b8*)(ws + OFF_WP);
    const b8* xB   = (const b8*)(ws + OFF_XB);

    const f32x4 zero4 = {0.f, 0.f, 0.f, 0.f};

    // zero h dbuf: 512 threads x 16B x 2
    *(f32x4*)(smem + tid * 16) = zero4;
    *(f32x4*)(smem + 8192 + tid * 16) = zero4;

    // stage this wave's 16 n-gate frags into LDS (one-time)
    {
        const b8* nsrc = wsN + (w * 16) * 64 + lane;
        b8* ndst = nlds + (w * 16) * 64 + lane;
        #pragma unroll
        for (int i = 0; i < 16; ++i) ndst[i * 64] = nsrc[i * 64];
    }

    // register-resident A-frags: r,z Whh (32 frags) + Wih (6 frags), PINNED
    b8 whr[2][8], whz[2][8], wir[2], wiz[2], win[2];
    #pragma unroll
    for (int nt = 0; nt < 2; ++nt) {
        #pragma unroll
        for (int kt = 0; kt < 8; ++kt) {
            whr[nt][kt] = wsRZ[((w * 4 + 0 + nt) * 8 + kt) * 64 + lane];
            whz[nt][kt] = wsRZ[((w * 4 + 2 + nt) * 8 + kt) * 64 + lane];
        }
        wir[nt] = wsWI[((w * 3 + 0) * 2 + nt) * 64 + lane];
        wiz[nt] = wsWI[((w * 3 + 1) * 2 + nt) * 64 + lane];
        win[nt] = wsWI[((w * 3 + 2) * 2 + nt) * 64 + lane];
    }
    #pragma unroll
    for (int nt = 0; nt < 2; ++nt) {
        #pragma unroll
        for (int kt = 0; kt < 8; ++kt) {
            asm volatile("" : "+v"(whr[nt][kt]));
            asm volatile("" : "+v"(whz[nt][kt]));
        }
        asm volatile("" : "+v"(wir[nt]));
        asm volatile("" : "+v"(wiz[nt]));
        asm volatile("" : "+v"(win[nt]));
    }

    // bhh_n accumulator-init values (C reg j <-> gatech 4*lq+j)
    const float4 bnv0 = *(const float4*)&bhh_f[2 * HDIM + 32 * w + 0  + 4 * lq];
    const float4 bnv1 = *(const float4*)&bhh_f[2 * HDIM + 32 * w + 16 + 4 * lq];

    // constant part of x B-frag: k=8 -> 1.0 (bias multiplier), rest 0
    b8 xc;
    #pragma unroll
    for (int e = 0; e < 8; ++e) xc[e] = (__bf16)0.0f;
    if (lq == 1) xc[0] = (__bf16)1.0f;

    // h master state in registers: (row=l15, ch=32w+16nt+4lq+j)
    f32x4 h0 = zero4, h1 = zero4;

    const int kswz = (8 * lq) ^ ((l15 & 7) << 3);     // B-read swizzle base
    const int wswz = (l15 & 7) << 3;                  // write swizzle
    const b8* nW = nlds + (w * 16) * 64 + lane;       // this wave's n frags in LDS
    const b8* xRow = xB + (blockRow + l15) * WDIM;

    // prefetch x for t=0
    b8 xf = xc;
    if (lane < 16) xf = xRow[0];

    __syncthreads();

    int cur = 0;
    for (int t = 0; t < WDIM; ++t) {
        // prefetch next step's x early (hides L2 latency under MFMA)
        b8 xn = xc;
        if (lane < 16) xn = xRow[(t < WDIM - 1) ? (t + 1) : t];

        const __bf16* hc = hbB + cur * 4096 + l15 * 256;

        f32x4 aR0 = zero4, aR1 = zero4;
        f32x4 aZ0 = zero4, aZ1 = zero4;
        f32x4 aNH0, aNH1;
        aNH0[0] = bnv0.x; aNH0[1] = bnv0.y; aNH0[2] = bnv0.z; aNH0[3] = bnv0.w;
        aNH1[0] = bnv1.x; aNH1[1] = bnv1.y; aNH1[2] = bnv1.z; aNH1[3] = bnv1.w;

        #pragma unroll
        for (int kt = 0; kt < 8; ++kt) {
            b8 hfrag = *(const b8*)(hc + ((kt << 5) ^ kswz));
            b8 n0 = nW[kt * 64];
            b8 n1 = nW[(8 + kt) * 64];
            aR0  = MFMA(whr[0][kt], hfrag, aR0);
            aR1  = MFMA(whr[1][kt], hfrag, aR1);
            aZ0  = MFMA(whz[0][kt], hfrag, aZ0);
            aZ1  = MFMA(whz[1][kt], hfrag, aZ1);
            aNH0 = MFMA(n0, hfrag, aNH0);
            aNH1 = MFMA(n1, hfrag, aNH1);
        }
        // x-part (+ biases via k=8 slot)
        aR0 = MFMA(wir[0], xf, aR0);
        aR1 = MFMA(wir[1], xf, aR1);
        aZ0 = MFMA(wiz[0], xf, aZ0);
        aZ1 = MFMA(wiz[1], xf, aZ1);
        f32x4 aNX0 = MFMA(win[0], xf, zero4);
        f32x4 aNX1 = MFMA(win[1], xf, zero4);

        // gate fusion (h master in regs)
        __bf16* hn = hbB + (cur ^ 1) * 4096;
        b4 v0, v1;
        #pragma unroll
        for (int j = 0; j < 4; ++j) {
            float r = sig_(aR0[j]);
            float z = sig_(aZ0[j]);
            float n = tanh_(fmaf(r, aNH0[j], aNX0[j]));
            float hv = n + z * (h0[j] - n);
            h0[j] = hv; v0[j] = (__bf16)hv;
            r = sig_(aR1[j]);
            z = sig_(aZ1[j]);
            n = tanh_(fmaf(r, aNH1[j], aNX1[j]));
            hv = n + z * (h1[j] - n);
            h1[j] = hv; v1[j] = (__bf16)hv;
        }
        *(b4*)(hn + l15 * 256 + ((32 * w + 0  + 4 * lq) ^ wswz)) = v0;
        *(b4*)(hn + l15 * 256 + ((32 * w + 16 + 4 * lq) ^ wswz)) = v1;

        xf = xn;
        cur ^= 1;
        __syncthreads();
    }

    // ---- write forward h (f32 regs) into lastb cols [0,256) ----
    {
        b4 v0, v1;
        #pragma unroll
        for (int j = 0; j < 4; ++j) { v0[j] = (__bf16)h0[j]; v1[j] = (__bf16)h1[j]; }
        *(b4*)(&lastb[l15][0] + ((32 * w + 0  + 4 * lq) ^ wswz)) = v0;
        *(b4*)(&lastb[l15][0] + ((32 * w + 16 + 4 * lq) ^ wswz)) = v1;
    }

    // ---- backward cell (h0=0, one step on x[:,127,:]) -> lastb cols [256,512) ----
    {
        const int trow = tid >> 5;           // 0..15
        const int cb = tid & 31;
        const float4* xr = (const float4*)(x + (blockRow + trow) * WDIM * FDIM + 127 * FDIM);
        float4 xv0 = xr[0], xv1 = xr[1];
        const float4* wb = (const float4*)Wih_b;
        #pragma unroll
        for (int jj = 0; jj < 8; ++jj) {
            int ch = cb + 32 * jj;
            float4 a0 = wb[ch * 2],              a1 = wb[ch * 2 + 1];
            float4 b0 = wb[(HDIM + ch) * 2],     b1 = wb[(HDIM + ch) * 2 + 1];
            float4 c0 = wb[(2 * HDIM + ch) * 2], c1 = wb[(2 * HDIM + ch) * 2 + 1];
            float ir = bih_b[ch]
                + xv0.x * a0.x + xv0.y * a0.y + xv0.z * a0.z + xv0.w * a0.w
                + xv1.x * a1.x + xv1.y * a1.y + xv1.z * a1.z + xv1.w * a1.w;
            float iz = bih_b[HDIM + ch]
                + xv0.x * b0.x + xv0.y * b0.y + xv0.z * b0.z + xv0.w * b0.w
                + xv1.x * b1.x + xv1.y * b1.y + xv1.z * b1.z + xv1.w * b1.w;
            float inn = bih_b[2 * HDIM + ch]
                + xv0.x * c0.x + xv0.y * c0.y + xv0.z * c0.z + xv0.w * c0.w
                + xv1.x * c1.x + xv1.y * c1.y + xv1.z * c1.z + xv1.w * c1.w;
            float r = sig_(ir + bhh_b[ch]);
            float z = sig_(iz + bhh_b[HDIM + ch]);
            float n = tanh_(fmaf(r, bhh_b[2 * HDIM + ch], inn));
            float hbw = (1.0f - z) * n;
            int c2 = HDIM + ch;
            lastb[trow][c2 ^ ((trow & 7) << 3)] = (__bf16)hbw;
        }
    }
    __syncthreads();

    // ---- projection: y = gelu(last @ Wp^T + bp); wave w -> cols [32w,32w+32) ----
    {
        f32x4 pacc[2];
        #pragma unroll
        for (int nt = 0; nt < 2; ++nt) {
            int col = 32 * w + nt * 16 + l15;
            float b = bp[col];
            pacc[nt][0] = b; pacc[nt][1] = b; pacc[nt][2] = b; pacc[nt][3] = b;
        }
        #pragma unroll
        for (int kt = 0; kt < 16; ++kt) {
            int c = (kt * 32 + lq * 8) ^ ((l15 & 7) << 3);
            b8 a = *(const b8*)&lastb[l15][c];
            #pragma unroll
            for (int nt = 0; nt < 2; ++nt)
                pacc[nt] = MFMA(a, wsWP[((2 * w + nt) * 16 + kt) * 64 + lane], pacc[nt]);
        }
        #pragma unroll
        for (int nt = 0; nt < 2; ++nt) {
            int col = 32 * w + nt * 16 + l15;
            #pragma unroll
            for (int j = 0; j < 4; ++j) {
                int row = lq * 4 + j;
                float v = pacc[nt][j];
                ybuf[row][col] = 0.5f * v * (1.0f + erff(v * 0.70710678118f));
            }
        }
    }
    __syncthreads();

    // ---- LayerNorm: one wave per 2 rows ----
    #pragma unroll
    for (int rr = 0; rr < 2; ++rr) {
        int row = 2 * w + rr;
        float v[4];
        float s = 0.0f, sq = 0.0f;
        #pragma unroll
        for (int m = 0; m < 4; ++m) {
            v[m] = ybuf[row][lane + 64 * m];
            s += v[m];
            sq += v[m] * v[m];
        }
        #pragma unroll
        for (int off = 32; off >= 1; off >>= 1) {
            s  += __shfl_xor(s, off, 64);
            sq += __shfl_xor(sq, off, 64);
        }
        float mu = s * (1.0f / 256.0f);
        float var = sq * (1.0f / 256.0f) - mu * mu;
        float rs = rsqrtf(var + 1e-5f);
        float* orow = out + (blockRow + row) * HDIM;
        #pragma unroll
        for (int m = 0; m < 4; ++m) {
            int cc = lane + 64 * m;
            orow[cc] = (v[m] - mu) * rs * gamma[cc] + beta[cc];
        }
    }
}

extern "C" void kernel_launch(void* const* d_in, const int* in_sizes, int n_in,
                              void* d_out, int out_size, void* d_ws, size_t ws_size,
                              hipStream_t stream)
{
    const float* x     = (const float*)d_in[0];
    const float* Wih_f = (const float*)d_in[1];
    const float* Whh_f = (const float*)d_in[2];
    const float* bih_f = (const float*)d_in[3];
    const float* bhh_f = (const float*)d_in[4];
    const float* Wih_b = (const float*)d_in[5];
    // d_in[6] = Whh_b unused: h0=0 so gh_b = bhh_b exactly
    const float* bih_b = (const float*)d_in[7];
    const float* bhh_b = (const float*)d_in[8];
    const float* Wp    = (const float*)d_in[9];
    const float* bp    = (const float*)d_in[10];
    const float* gamma = (const float*)d_in[11];
    const float* beta  = (const float*)d_in[12];
    float* out = (float*)d_out;
    unsigned char* ws = (unsigned char*)d_ws;

    // allow 144KB dynamic LDS (idempotent; host-side attribute, not a stream op)
    hipFuncSetAttribute((const void*)gru_main_kernel,
                        hipFuncAttributeMaxDynamicSharedMemorySize, SMEM_BYTES);

    const int packItems = 16384 + 8192 + 3072 + 16384 + 262144;   // 306176
    hipLaunchKernelGGL(pack_kernel, dim3((packItems + 255) / 256), dim3(256), 0, stream,
                       x, Wih_f, Whh_f, bih_f, bhh_f, Wp, ws);
    hipLaunchKernelGGL(gru_main_kernel, dim3(BDIM / 16), dim3(512), SMEM_BYTES, stream,
                       x, bhh_f, Wih_b, bih_b, bhh_b, bp, gamma, beta, ws, out);
}